// Round 4
// baseline (37688.419 us; speedup 1.0000x reference)
//
#include <hip/hip_runtime.h>
#include <hip/hip_fp16.h>

typedef _Float16 h2f __attribute__((ext_vector_type(2)));

#define RB 64
#define RT 2048
#define RI 64
#define RH 512
#define C1F 0.9f
#define C2F 0.1f

#define NQ 4          // column quarters (blocks per batch)
#define QC 128        // columns per quarter
#define NG 72         // k-groups of 8 rows: 64 h-groups + 8 x-groups
#define THL (RH + RI) // extended state [tanh(h); x_t] = 576

// d_ws layout (bytes)
#define P_OFF  0
#define P_SZ   (NQ * NG * QC * 16)      // 589824: packed f16 W, per-quarter
#define XD_OFF (P_OFF + P_SZ)
#define XD_SZ  (2 * RB * NQ * QC * 2)   // 131072: tanh exchange, 2 slots
#define FL_OFF (XD_OFF + XD_SZ)
#define FL_SZ  (2 * RB * NQ * 4)        // 2048: generation flags

static __device__ __forceinline__ h2f bch2(unsigned int v) {
    return __builtin_bit_cast(h2f, v);
}

#if __has_builtin(__builtin_amdgcn_fdot2)
#define DOT2(a, b, c) __builtin_amdgcn_fdot2((a), (b), (c), false)
#else
#define DOT2(a, b, c) fmaf((float)(a).x, (float)(b).x, fmaf((float)(a).y, (float)(b).y, (c)))
#endif

// Pack [W_hidden; W_in] columns into per-quarter f16-pair stream.
// h2f entry e = ((q*NG + u)*QC + col)*4 + qq holds rows (8u+2qq, 8u+2qq+1)
// of global column q*QC+col. uint4 entry (q*NG+u)*QC+col = rows 8u..8u+7.
__global__ void prep_pack(const float* __restrict__ W, const float* __restrict__ Win,
                          h2f* __restrict__ P) {
    int e = blockIdx.x * 256 + threadIdx.x;
    if (e >= NQ * NG * QC * 4) return;
    int qq   = e & 3;
    int col  = (e >> 2) & (QC - 1);
    int u    = (e >> 9) % NG;
    int q    = (e >> 9) / NG;
    int colg = q * QC + col;
    int k    = 8 * u + 2 * qq;
    float v0, v1;
    if (u < 64) { v0 = W[k * RH + colg];          v1 = W[(k + 1) * RH + colg]; }
    else        { int i = k - RH;
                  v0 = Win[i * RH + colg];        v1 = Win[(i + 1) * RH + colg]; }
    h2f r; r.x = (_Float16)v0; r.y = (_Float16)v1;
    P[e] = r;
}

// Grid: 256 blocks, blockIdx = q*64 + b (all 4 quarters of a batch land on the
// same XCD under round-robin dispatch). 256 threads: col = tid>>1 (0..127),
// kh = tid&1 splits the 72 k-groups 36/36; lane-pair reduce via shfl_xor(1).
// W-quarter fully LDS-resident (147 KB). tanh exchanged through L2 with
// release/acquire generation flags (2-slot ping-pong, lockstep-safe).
__global__ __launch_bounds__(256) void rnn_scan(
        const float* __restrict__ x,      // [RB][RT][RI] f32
        const float* __restrict__ sigma,  // [RB][RT][RH] f32
        const float* __restrict__ h0,     // [RB][RH]     f32
        const uint4* __restrict__ P,      // packed W (see prep_pack)
        float* __restrict__ out,          // [RB][RT][RH] f32, then h_f [RB][RH]
        _Float16* __restrict__ XD,        // [2][RB][NQ][QC] exchange data
        unsigned* __restrict__ FL)        // [2][RB][NQ]     generation flags
{
    const int bid  = blockIdx.x;
    const int q    = bid >> 6;
    const int b    = bid & 63;
    const int tid  = threadIdx.x;
    const int col  = tid >> 1;
    const int kh   = tid & 1;
    const int colg = q * QC + col;
    const int w    = tid >> 6;     // wave 0..3
    const int lane = tid & 63;

    __shared__ __align__(16) uint4    Wl[NG * QC];   // 147456 B
    __shared__ __align__(16) _Float16 th[2][THL];    // 2304 B

    // W-quarter -> LDS (coalesced)
    const uint4* Pq = P + q * NG * QC;
    for (int e = tid; e < NG * QC; e += 256)
        Wl[e] = Pq[e];

    const float* xrow = x + (size_t)b * RT * RI;
    const float* srow = sigma + (size_t)b * RT * RH;
    float*       orow = out + (size_t)b * RT * RH;

    float h = h0[b * RH + colg];

    // ---- init: publish th for step 0 (slot 0, generation 1)
    {
        float e2 = __expf(2.0f * h);
        float tv = 1.0f - 2.0f / (e2 + 1.0f);
        if (kh == 0) {
            th[0][colg] = (_Float16)tv;
            XD[(size_t)((0 * RB + b) * NQ + q) * QC + col] = (_Float16)tv;
        }
        if (w == 0) th[0][RH + lane] = (_Float16)xrow[lane];
        __syncthreads();
        if (tid == 0) {
            __threadfence();
            __hip_atomic_store(&FL[(0 * RB + b) * NQ + q], 1u,
                               __ATOMIC_RELEASE, __HIP_MEMORY_SCOPE_AGENT);
        }
        if (w >= 1) {
            int qp = (q + w) & 3;
            unsigned* fp = &FL[(0 * RB + b) * NQ + qp];
            while (__hip_atomic_load(fp, __ATOMIC_ACQUIRE,
                                     __HIP_MEMORY_SCOPE_AGENT) < 1u) {}
            const unsigned* src =
                (const unsigned*)&XD[(size_t)((0 * RB + b) * NQ + qp) * QC];
            ((unsigned*)&th[0][qp * QC])[lane] = src[lane];
        }
        __syncthreads();
    }

    for (int t = 0; t < RT; ++t) {
        const int cs = t & 1;
        const uint4* thq = (const uint4*)th[cs];
        float sg = srow[(size_t)t * RH + colg];

        // 36 k-groups for this thread's k-half; W from LDS (even-banked
        // contiguous b128), th via 2-way uniform broadcast reads.
        float a0 = 0.f, a1 = 0.f, a2 = 0.f, a3 = 0.f;
        const uint4* Wk = &Wl[kh * 36 * QC + col];
        #pragma unroll
        for (int i = 0; i < 36; ++i) {
            uint4 tv = thq[kh * 36 + i];
            uint4 wv = Wk[i * QC];
            a0 = DOT2(bch2(wv.x), bch2(tv.x), a0);
            a1 = DOT2(bch2(wv.y), bch2(tv.y), a1);
            a2 = DOT2(bch2(wv.z), bch2(tv.z), a2);
            a3 = DOT2(bch2(wv.w), bch2(tv.w), a3);
        }
        float a = (a0 + a1) + (a2 + a3);
        a += __shfl_xor(a, 1);         // join the two k-halves (lane pair)

        float hn = C1F * h + C2F * a + sg;
        if (kh == 0) orow[(size_t)t * RH + colg] = hn;
        h = hn;

        if (t + 1 < RT) {
            const int ns = cs ^ 1;
            const unsigned target = (unsigned)(t + 2);
            float e2 = __expf(2.0f * hn);
            float tv = 1.0f - 2.0f / (e2 + 1.0f);
            if (kh == 0) {
                th[ns][colg] = (_Float16)tv;
                XD[(size_t)((ns * RB + b) * NQ + q) * QC + col] = (_Float16)tv;
            }
            if (w == 0) th[ns][RH + lane] = (_Float16)xrow[(size_t)(t + 1) * RI + lane];
            __syncthreads();           // own posts done
            if (tid == 0) {
                __threadfence();
                __hip_atomic_store(&FL[(ns * RB + b) * NQ + q], target,
                                   __ATOMIC_RELEASE, __HIP_MEMORY_SCOPE_AGENT);
            }
            if (w >= 1) {              // wave w fetches peer (q+w)&3
                int qp = (q + w) & 3;
                unsigned* fp = &FL[(ns * RB + b) * NQ + qp];
                while (__hip_atomic_load(fp, __ATOMIC_ACQUIRE,
                                         __HIP_MEMORY_SCOPE_AGENT) < target) {}
                const unsigned* src =
                    (const unsigned*)&XD[(size_t)((ns * RB + b) * NQ + qp) * QC];
                ((unsigned*)&th[ns][qp * QC])[lane] = src[lane];
            }
            __syncthreads();           // th[ns] complete
        }
    }

    if (kh == 0)
        out[(size_t)RB * RT * RH + (size_t)b * RH + colg] = h;
}

extern "C" void kernel_launch(void* const* d_in, const int* in_sizes, int n_in,
                              void* d_out, int out_size, void* d_ws, size_t ws_size,
                              hipStream_t stream) {
    const float* x   = (const float*)d_in[0];
    const float* Win = (const float*)d_in[1];
    const float* Wh  = (const float*)d_in[2];
    const float* sg  = (const float*)d_in[3];
    const float* h0  = (const float*)d_in[4];
    float* out = (float*)d_out;

    h2f*      P  = (h2f*)((char*)d_ws + P_OFF);
    _Float16* XD = (_Float16*)((char*)d_ws + XD_OFF);
    unsigned* FL = (unsigned*)((char*)d_ws + FL_OFF);

    // flags must start at 0 every call (deterministic under graph replay)
    hipMemsetAsync((char*)d_ws + FL_OFF, 0, FL_SZ, stream);

    const int n_entries = NQ * NG * QC * 4;
    hipLaunchKernelGGL(prep_pack, dim3((n_entries + 255) / 256), dim3(256), 0, stream,
                       Wh, Win, P);
    hipLaunchKernelGGL(rnn_scan, dim3(RB * NQ), dim3(256), 0, stream,
                       x, sg, h0, (const uint4*)((char*)d_ws + P_OFF), out, XD, FL);
}

// Round 5
// 11879.321 us; speedup vs baseline: 3.1726x; 3.1726x over previous
//
#include <hip/hip_runtime.h>
#include <hip/hip_fp16.h>

typedef _Float16 h2f __attribute__((ext_vector_type(2)));

#define RB 64
#define RT 2048
#define RI 64
#define RH 512
#define C1F 0.9f
#define C2F 0.1f

// 72 k-groups of 8 rows: 64 W_hidden groups + 8 W_in groups (input projection
// folded into the recurrence as extra K-rows).
#define NU     72
#define NU_REG 8                       // u 0..7   -> pinned VGPRs (32 regs)
#define NU_LDS 16                      // u 8..23  -> LDS-resident (128 KB)
#define NCH    12                      // u 24..71 -> streamed, 12 chunks x 4 groups
#define THL    (RH + RI)               // extended state [tanh(h); x_t] = 576

static __device__ __forceinline__ h2f bch2(unsigned int v) {
    return __builtin_bit_cast(h2f, v);
}

#if __has_builtin(__builtin_amdgcn_fdot2)
#define DOT2(a, b, c) __builtin_amdgcn_fdot2((a), (b), (c), false)
#else
#define DOT2(a, b, c) fmaf((float)(a).x, (float)(b).x, fmaf((float)(a).y, (float)(b).y, (c)))
#endif

// Pack [W_hidden; W_in] to f16 pairs.
// Region A (u 0..23, REG+LDS tiers): plain [u][j] — uint4 idx u*RH+j holds
//   rows 8u..8u+7 of column j (16B-stride lanes: coalesced + conflict-free).
// Region S (u 24..71, streamed): chunked [c][j][r], c=0..11, r=0..3,
//   uint4 idx 24*RH + c*4*RH + j*4 + r holds rows of group u=24+4c+r.
//   Per thread a chunk is 4 consecutive uint4 -> one base + imm offsets
//   0/16/32/48 (zero per-load address arithmetic in the scan).
__global__ void prep_pack(const float* __restrict__ W, const float* __restrict__ Win,
                          h2f* __restrict__ P) {
    int e = blockIdx.x * 256 + threadIdx.x;
    if (e >= NU * RH * 4) return;
    int u, j, q;
    if (e < (NU_REG + NU_LDS) * RH * 4) {       // region A: 24*2048 h2f entries
        u = e >> 11;
        j = (e >> 2) & (RH - 1);
        q = e & 3;
    } else {                                    // region S
        int s = e - (NU_REG + NU_LDS) * RH * 4;
        int c = s >> 13;                        // 8192 h2f per chunk
        int i = s & 8191;                       // = j*16 + r*4 + q
        j = i >> 4;
        int r = (i >> 2) & 3;
        q = i & 3;
        u = (NU_REG + NU_LDS) + 4 * c + r;
    }
    int k = 8 * u + 2 * q;
    float v0, v1;
    if (u < 64) { v0 = W[k * RH + j];              v1 = W[(k + 1) * RH + j]; }
    else        { int i2 = k - RH;
                  v0 = Win[i2 * RH + j];           v1 = Win[(i2 + 1) * RH + j]; }
    h2f r2; r2.x = (_Float16)v0; r2.y = (_Float16)v1;
    P[e] = r2;
}

// One block per batch element; thread j owns column j (consecutive lanes ->
// 16B-stride LDS reads, measured conflict-free). W column lives in:
// 32 pinned VGPRs + 128 KB LDS + 384 KB/step L2 stream (imm-offset chunks).
// State [tanh(h); x_t] is f16 in LDS, double-buffered -> one barrier/step.
__global__ __launch_bounds__(RH, 2) void rnn_scan(
        const float* __restrict__ x,      // [RB][RT][RI] f32
        const float* __restrict__ sigma,  // [RB][RT][RH] f32
        const float* __restrict__ h0,     // [RB][RH]     f32
        const uint4* __restrict__ P,      // packed f16 W (see prep_pack)
        float* __restrict__ out)          // [RB][RT][RH] f32, then h_f [RB][RH]
{
    const int b = blockIdx.x;
    const int j = threadIdx.x;

    __shared__ __align__(16) uint4    Wl[NU_LDS * RH];   // 131072 B
    __shared__ __align__(16) _Float16 th[2][THL];        // 2304 B

    // LDS tier (groups 8..23), coalesced fill
    for (int e = j; e < NU_LDS * RH; e += RH)
        Wl[e] = P[NU_REG * RH + e];

    // REG tier (groups 0..7): small pin (32 VGPR) the allocator can afford;
    // asm result is non-rematerializable -> stays in registers.
    uint4 wr[NU_REG];
    #pragma unroll
    for (int u = 0; u < NU_REG; ++u)
        wr[u] = P[u * RH + j];
    #pragma unroll
    for (int u = 0; u < NU_REG; ++u)
        asm volatile("" : "+v"(wr[u].x), "+v"(wr[u].y), "+v"(wr[u].z), "+v"(wr[u].w));

    // two LDS bases so all 16 W-reads use ds imm offsets (<=57344)
    const uint4* Wl0 = &Wl[j];
    const uint4* Wl8 = &Wl[8 * RH + j];

    const float* xrow = x + (size_t)b * RT * RI;
    const float* srow = sigma + (size_t)b * RT * RH;
    float*       orow = out + (size_t)b * RT * RH;

    float h = h0[b * RH + j];
    {
        float e2 = __expf(2.0f * h);
        th[0][j] = (_Float16)(1.0f - 2.0f / (e2 + 1.0f));
    }
    if (j < RI) th[0][RH + j] = (_Float16)xrow[j];
    __syncthreads();

    for (int t = 0; t < RT; ++t) {
        const uint4* thq = (const uint4*)th[t & 1];
        _Float16*    thw = th[(t & 1) ^ 1];

        float sg = srow[(size_t)t * RH + j];
        float xn = 0.0f;
        if (j < RI && t + 1 < RT) xn = xrow[(size_t)(t + 1) * RI + j];

        // opaque 0 renews the stream base each step: loads can't be hoisted
        // across the t-loop (would pin 192 regs and spill, round-3 lesson).
        int off0 = 0;
        asm volatile("" : "+v"(off0));
        const uint4* Sb = P + (size_t)(NU_REG + NU_LDS) * RH + 4 * j + off0;

        float a0 = 0.f, a1 = 0.f, a2 = 0.f, a3 = 0.f;

        #pragma unroll
        for (int u = 0; u < NU_REG; ++u) {      // register tier
            uint4 tv = thq[u];
            uint4 wv = wr[u];
            a0 = DOT2(bch2(wv.x), bch2(tv.x), a0);
            a1 = DOT2(bch2(wv.y), bch2(tv.y), a1);
            a2 = DOT2(bch2(wv.z), bch2(tv.z), a2);
            a3 = DOT2(bch2(wv.w), bch2(tv.w), a3);
        }
        #pragma unroll
        for (int u = 0; u < 8; ++u) {           // LDS tier, first base
            uint4 tv = thq[NU_REG + u];
            uint4 wv = Wl0[u * RH];
            a0 = DOT2(bch2(wv.x), bch2(tv.x), a0);
            a1 = DOT2(bch2(wv.y), bch2(tv.y), a1);
            a2 = DOT2(bch2(wv.z), bch2(tv.z), a2);
            a3 = DOT2(bch2(wv.w), bch2(tv.w), a3);
        }
        #pragma unroll
        for (int u = 0; u < 8; ++u) {           // LDS tier, second base
            uint4 tv = thq[NU_REG + 8 + u];
            uint4 wv = Wl8[u * RH];
            a0 = DOT2(bch2(wv.x), bch2(tv.x), a0);
            a1 = DOT2(bch2(wv.y), bch2(tv.y), a1);
            a2 = DOT2(bch2(wv.z), bch2(tv.z), a2);
            a3 = DOT2(bch2(wv.w), bch2(tv.w), a3);
        }
        #pragma unroll
        for (int c = 0; c < NCH; ++c) {         // streamed tier
            const uint4* p = Sb + c * (4 * RH);
            uint4 w0 = p[0], w1 = p[1], w2 = p[2], w3 = p[3];  // imm 0/16/32/48
            const int ub = NU_REG + NU_LDS + 4 * c;
            uint4 t0 = thq[ub], t1 = thq[ub + 1], t2 = thq[ub + 2], t3 = thq[ub + 3];
            a0 = DOT2(bch2(w0.x), bch2(t0.x), a0);
            a1 = DOT2(bch2(w0.y), bch2(t0.y), a1);
            a2 = DOT2(bch2(w0.z), bch2(t0.z), a2);
            a3 = DOT2(bch2(w0.w), bch2(t0.w), a3);
            a0 = DOT2(bch2(w1.x), bch2(t1.x), a0);
            a1 = DOT2(bch2(w1.y), bch2(t1.y), a1);
            a2 = DOT2(bch2(w1.z), bch2(t1.z), a2);
            a3 = DOT2(bch2(w1.w), bch2(t1.w), a3);
            a0 = DOT2(bch2(w2.x), bch2(t2.x), a0);
            a1 = DOT2(bch2(w2.y), bch2(t2.y), a1);
            a2 = DOT2(bch2(w2.z), bch2(t2.z), a2);
            a3 = DOT2(bch2(w2.w), bch2(t2.w), a3);
            a0 = DOT2(bch2(w3.x), bch2(t3.x), a0);
            a1 = DOT2(bch2(w3.y), bch2(t3.y), a1);
            a2 = DOT2(bch2(w3.z), bch2(t3.z), a2);
            a3 = DOT2(bch2(w3.w), bch2(t3.w), a3);
        }

        float hn = C1F * h + C2F * ((a0 + a1) + (a2 + a3)) + sg;
        orow[(size_t)t * RH + j] = hn;
        h = hn;

        float e2 = __expf(2.0f * hn);
        thw[j] = (_Float16)(1.0f - 2.0f / (e2 + 1.0f));
        if (j < RI && t + 1 < RT) thw[RH + j] = (_Float16)xn;
        __syncthreads();
    }

    out[(size_t)RB * RT * RH + (size_t)b * RH + j] = h;
}

extern "C" void kernel_launch(void* const* d_in, const int* in_sizes, int n_in,
                              void* d_out, int out_size, void* d_ws, size_t ws_size,
                              hipStream_t stream) {
    const float* x   = (const float*)d_in[0];
    const float* Win = (const float*)d_in[1];
    const float* Wh  = (const float*)d_in[2];
    const float* sg  = (const float*)d_in[3];
    const float* h0  = (const float*)d_in[4];
    float* out = (float*)d_out;

    h2f* P = (h2f*)d_ws;   // 576 KB packed [W_hidden; W_in]

    const int n_entries = NU * RH * 4;
    hipLaunchKernelGGL(prep_pack, dim3((n_entries + 255) / 256), dim3(256), 0, stream,
                       Wh, Win, P);
    hipLaunchKernelGGL(rnn_scan, dim3(RB), dim3(RH), 0, stream,
                       x, sg, h0, (const uint4*)d_ws, out);
}

// Round 6
// 6724.663 us; speedup vs baseline: 5.6045x; 1.7665x over previous
//
#include <hip/hip_runtime.h>
#include <hip/hip_fp16.h>

typedef _Float16 h2f __attribute__((ext_vector_type(2)));

#define RB 64
#define RT 2048
#define RI 64
#define RH 512
#define C1F 0.9f
#define C2F 0.1f

// 72 k-groups of 8 rows: 64 W_hidden groups + 8 W_in groups (input projection
// folded into the recurrence as extra K-rows).
#define NU     72
#define NU_REG 8                       // u 0..7   -> pinned VGPRs (32 regs, proven)
#define NU_LDS 19                      // u 8..26  -> LDS-resident (152 KB)
#define NU_STR (NU - NU_REG - NU_LDS)  // u 27..71 -> streamed, [u][j] coalesced
#define THL    (RH + RI)               // extended state [tanh(h); x_t] = 576

static __device__ __forceinline__ h2f bch2(unsigned int v) {
    return __builtin_bit_cast(h2f, v);
}

#if __has_builtin(__builtin_amdgcn_fdot2)
#define DOT2(a, b, c) __builtin_amdgcn_fdot2((a), (b), (c), false)
#else
#define DOT2(a, b, c) fmaf((float)(a).x, (float)(b).x, fmaf((float)(a).y, (float)(b).y, (c)))
#endif

// Pack [W_hidden; W_in] to f16 pairs, plain [u][j] everywhere:
// uint4 entry u*RH + j holds rows 8u..8u+7 of column j. Lane stride is 16 B
// in the scan kernel -> coalesced global loads and conflict-free ds reads
// (the one layout rounds 2/3 measured at zero conflicts / zero amplification).
__global__ void prep_pack(const float* __restrict__ W, const float* __restrict__ Win,
                          h2f* __restrict__ P) {
    int e = blockIdx.x * 256 + threadIdx.x;
    if (e >= NU * RH * 4) return;
    int q = e & 3;
    int j = (e >> 2) & (RH - 1);
    int u = e >> 11;
    int k = 8 * u + 2 * q;
    float v0, v1;
    if (u < 64) { v0 = W[k * RH + j];          v1 = W[(k + 1) * RH + j]; }
    else        { int i = k - RH;
                  v0 = Win[i * RH + j];        v1 = Win[(i + 1) * RH + j]; }
    h2f r; r.x = (_Float16)v0; r.y = (_Float16)v1;
    P[e] = r;
}

// One block per batch element; thread j owns column j. W column lives in:
// 32 pinned VGPRs + 152 KB LDS + 360 KB/step coalesced L2 stream.
// State [tanh(h); x_t] is f16 in LDS, double-buffered -> one barrier/step.
__global__ __launch_bounds__(RH, 2) void rnn_scan(
        const float* __restrict__ x,      // [RB][RT][RI] f32
        const float* __restrict__ sigma,  // [RB][RT][RH] f32
        const float* __restrict__ h0,     // [RB][RH]     f32
        const uint4* __restrict__ P,      // packed f16 W (see prep_pack)
        float* __restrict__ out)          // [RB][RT][RH] f32, then h_f [RB][RH]
{
    const int b = blockIdx.x;
    const int j = threadIdx.x;

    __shared__ __align__(16) uint4    Wl[NU_LDS * RH];   // 155648 B
    __shared__ __align__(16) _Float16 th[2][THL];        // 2304 B

    // LDS tier (groups 8..26), coalesced fill
    for (int e = j; e < NU_LDS * RH; e += RH)
        Wl[e] = P[NU_REG * RH + e];

    // REG tier (groups 0..7): small pin the allocator tolerates (round 5:
    // VGPR 88, no spill). asm result is non-rematerializable.
    uint4 wr[NU_REG];
    #pragma unroll
    for (int u = 0; u < NU_REG; ++u)
        wr[u] = P[u * RH + j];
    #pragma unroll
    for (int u = 0; u < NU_REG; ++u)
        asm volatile("" : "+v"(wr[u].x), "+v"(wr[u].y), "+v"(wr[u].z), "+v"(wr[u].w));

    // three LDS bases so every W-read uses a ds imm offset (max 57344 < 65536)
    const uint4* Wl0  = &Wl[j];
    const uint4* Wl8  = &Wl[8 * RH + j];
    const uint4* Wl16 = &Wl[16 * RH + j];

    const float* xrow = x + (size_t)b * RT * RI;
    const float* srow = sigma + (size_t)b * RT * RH;
    float*       orow = out + (size_t)b * RT * RH;

    float h = h0[b * RH + j];
    {
        float e2 = __expf(2.0f * h);
        th[0][j] = (_Float16)(1.0f - 2.0f / (e2 + 1.0f));
    }
    if (j < RI) th[0][RH + j] = (_Float16)xrow[j];
    __syncthreads();

    for (int t = 0; t < RT; ++t) {
        const uint4* thq = (const uint4*)th[t & 1];
        _Float16*    thw = th[(t & 1) ^ 1];

        float sg = srow[(size_t)t * RH + j];
        float xn = 0.0f;
        if (j < RI && t + 1 < RT) xn = xrow[(size_t)(t + 1) * RI + j];

        // opaque 0 renews the stream base each step: the 45 loads cannot be
        // hoisted across the t-loop (round-3 spill lesson), but within the
        // step the scheduler pipelines them ahead of their dot2 consumers.
        int off0 = 0;
        asm volatile("" : "+v"(off0));
        const uint4* Pst = P + (size_t)(NU_REG + NU_LDS) * RH + j + off0;

        float a0 = 0.f, a1 = 0.f, a2 = 0.f, a3 = 0.f;

        #pragma unroll
        for (int u = 0; u < NU_REG; ++u) {      // register tier
            uint4 tv = thq[u];
            uint4 wv = wr[u];
            a0 = DOT2(bch2(wv.x), bch2(tv.x), a0);
            a1 = DOT2(bch2(wv.y), bch2(tv.y), a1);
            a2 = DOT2(bch2(wv.z), bch2(tv.z), a2);
            a3 = DOT2(bch2(wv.w), bch2(tv.w), a3);
        }
        #pragma unroll
        for (int u = 0; u < 8; ++u) {           // LDS tier, base 0
            uint4 tv = thq[NU_REG + u];
            uint4 wv = Wl0[u * RH];
            a0 = DOT2(bch2(wv.x), bch2(tv.x), a0);
            a1 = DOT2(bch2(wv.y), bch2(tv.y), a1);
            a2 = DOT2(bch2(wv.z), bch2(tv.z), a2);
            a3 = DOT2(bch2(wv.w), bch2(tv.w), a3);
        }
        #pragma unroll
        for (int u = 0; u < 8; ++u) {           // LDS tier, base 8
            uint4 tv = thq[NU_REG + 8 + u];
            uint4 wv = Wl8[u * RH];
            a0 = DOT2(bch2(wv.x), bch2(tv.x), a0);
            a1 = DOT2(bch2(wv.y), bch2(tv.y), a1);
            a2 = DOT2(bch2(wv.z), bch2(tv.z), a2);
            a3 = DOT2(bch2(wv.w), bch2(tv.w), a3);
        }
        #pragma unroll
        for (int u = 0; u < 3; ++u) {           // LDS tier, base 16
            uint4 tv = thq[NU_REG + 16 + u];
            uint4 wv = Wl16[u * RH];
            a0 = DOT2(bch2(wv.x), bch2(tv.x), a0);
            a1 = DOT2(bch2(wv.y), bch2(tv.y), a1);
            a2 = DOT2(bch2(wv.z), bch2(tv.z), a2);
            a3 = DOT2(bch2(wv.w), bch2(tv.w), a3);
        }
        #pragma unroll
        for (int u = 0; u < NU_STR; ++u) {      // streamed tier, coalesced
            uint4 tv = thq[NU_REG + NU_LDS + u];
            uint4 wv = Pst[u * RH];
            a0 = DOT2(bch2(wv.x), bch2(tv.x), a0);
            a1 = DOT2(bch2(wv.y), bch2(tv.y), a1);
            a2 = DOT2(bch2(wv.z), bch2(tv.z), a2);
            a3 = DOT2(bch2(wv.w), bch2(tv.w), a3);
        }

        float hn = C1F * h + C2F * ((a0 + a1) + (a2 + a3)) + sg;
        orow[(size_t)t * RH + j] = hn;
        h = hn;

        float e2 = __expf(2.0f * hn);
        thw[j] = (_Float16)(1.0f - 2.0f / (e2 + 1.0f));
        if (j < RI && t + 1 < RT) thw[RH + j] = (_Float16)xn;
        __syncthreads();
    }

    out[(size_t)RB * RT * RH + (size_t)b * RH + j] = h;
}

extern "C" void kernel_launch(void* const* d_in, const int* in_sizes, int n_in,
                              void* d_out, int out_size, void* d_ws, size_t ws_size,
                              hipStream_t stream) {
    const float* x   = (const float*)d_in[0];
    const float* Win = (const float*)d_in[1];
    const float* Wh  = (const float*)d_in[2];
    const float* sg  = (const float*)d_in[3];
    const float* h0  = (const float*)d_in[4];
    float* out = (float*)d_out;

    h2f* P = (h2f*)d_ws;   // 576 KB packed [W_hidden; W_in]

    const int n_entries = NU * RH * 4;
    hipLaunchKernelGGL(prep_pack, dim3((n_entries + 255) / 256), dim3(256), 0, stream,
                       Wh, Win, P);
    hipLaunchKernelGGL(rnn_scan, dim3(RB), dim3(RH), 0, stream,
                       x, sg, h0, (const uint4*)d_ws, out);
}

// Round 7
// 6684.937 us; speedup vs baseline: 5.6378x; 1.0059x over previous
//
#include <hip/hip_runtime.h>
#include <hip/hip_fp16.h>

typedef _Float16 h2f  __attribute__((ext_vector_type(2)));
typedef _Float16 half8 __attribute__((ext_vector_type(8)));
typedef float    f32x4 __attribute__((ext_vector_type(4)));

#define RB 64
#define RT 2048
#define RI 64
#define RH 512
#define C1F 0.9f
#define C2F 0.1f

// 72 u-groups of 8 k-rows (64 W_hidden + 8 W_in), = 18 MFMA k-steps of 32.
#define NU      72
#define PIN_KS  2     // k-steps 0..1   (u 0..7)   -> pinned VGPR B-frags (32 regs)
#define LDS_KS  4     // k-steps 2..5   (u 8..23)  -> LDS-resident (128 KB)
#define STR_KS  12    // k-steps 6..17  (u 24..71) -> streamed (384 KB/step)
#define THL     (RH + RI)   // extended state [tanh(h); x_t] = 576 halves

static __device__ __forceinline__ half8 bc8(uint4 v) {
    return __builtin_bit_cast(half8, v);
}

#define MFMA(a, b, c) __builtin_amdgcn_mfma_f32_16x16x32_f16((a), (b), (c), 0, 0, 0)

// Pack [W_hidden; W_in] to f16, plain [u][j]: uint4 entry u*RH+j holds rows
// 8u..8u+7 of column j. This is simultaneously (a) a coalesced 16B-lane-stride
// stream layout and (b) exactly one MFMA B-subfragment: B-frag for k-window
// 4c..4c+3, col-tile base cb is lane l -> P[(4c + (l>>4))*RH + cb + (l&15)].
__global__ void prep_pack(const float* __restrict__ W, const float* __restrict__ Win,
                          h2f* __restrict__ P) {
    int e = blockIdx.x * 256 + threadIdx.x;
    if (e >= NU * RH * 4) return;
    int q = e & 3;
    int j = (e >> 2) & (RH - 1);
    int u = e >> 11;
    int k = 8 * u + 2 * q;
    float v0, v1;
    if (u < 64) { v0 = W[k * RH + j];          v1 = W[(k + 1) * RH + j]; }
    else        { int i = k - RH;
                  v0 = Win[i * RH + j];        v1 = Win[(i + 1) * RH + j]; }
    h2f r; r.x = (_Float16)v0; r.y = (_Float16)v1;
    P[e] = r;
}

// One block per batch element; 8 waves; wave w owns cols w*64..w*64+63;
// lane l finalizes col w*64+l (C/D: col=lane&15, rows identical by A-broadcast).
__global__ __launch_bounds__(RH, 2) void rnn_scan(
        const float* __restrict__ x,      // [RB][RT][RI] f32
        const float* __restrict__ sigma,  // [RB][RT][RH] f32
        const float* __restrict__ h0,     // [RB][RH]     f32
        const uint4* __restrict__ P,      // packed f16 W (see prep_pack)
        float* __restrict__ out)          // [RB][RT][RH] f32, then h_f [RB][RH]
{
    const int b    = blockIdx.x;
    const int tid  = threadIdx.x;
    const int wave = tid >> 6;
    const int lane = tid & 63;
    const int g    = lane >> 4;          // 16-lane group = B k-subrow / C row-group
    const int li   = lane & 15;          // B/C column within tile
    const int wb   = wave * 64;          // wave's column base
    const int col  = wb + lane;          // this lane's output column

    __shared__ __align__(16) uint4    Wl[LDS_KS * 4 * RH];  // 131072 B
    __shared__ __align__(16) _Float16 th[2][THL];           // 2304 B

    // LDS tier: u-groups 8..23
    for (int e = tid; e < LDS_KS * 4 * RH; e += RH)
        Wl[e] = P[8 * RH + e];

    // pinned B-frags: k-steps 0..1, tiles n=0..3 (asm pin = non-rematerializable)
    uint4 bp[PIN_KS][4];
    #pragma unroll
    for (int c = 0; c < PIN_KS; ++c)
        #pragma unroll
        for (int n = 0; n < 4; ++n)
            bp[c][n] = P[(4 * c + g) * RH + wb + n * 16 + li];
    #pragma unroll
    for (int c = 0; c < PIN_KS; ++c)
        #pragma unroll
        for (int n = 0; n < 4; ++n)
            asm volatile("" : "+v"(bp[c][n].x), "+v"(bp[c][n].y),
                               "+v"(bp[c][n].z), "+v"(bp[c][n].w));

    const float* xrow = x + (size_t)b * RT * RI;
    const float* srow = sigma + (size_t)b * RT * RH;
    float*       orow = out + (size_t)b * RT * RH;

    float h = h0[b * RH + col];
    {
        float e2 = __expf(2.0f * h);
        th[0][col] = (_Float16)(1.0f - 2.0f / (e2 + 1.0f));
    }
    if (tid < RI) th[0][RH + tid] = (_Float16)xrow[tid];
    __syncthreads();

    for (int t = 0; t < RT; ++t) {
        const uint4* thq = (const uint4*)th[t & 1];
        _Float16*    thw = th[(t & 1) ^ 1];

        float sg = srow[(size_t)t * RH + col];
        float xn = 0.0f;
        if (tid < RI && t + 1 < RT) xn = xrow[(size_t)(t + 1) * RI + tid];

        // streamed tier base; opaque 0 keeps the 48 loads inside the t-loop
        int off0 = 0;
        asm volatile("" : "+v"(off0));
        const uint4* Pst = P + (size_t)(24 + g) * RH + wb + li + off0;

        f32x4 acc0 = {0.f, 0.f, 0.f, 0.f};
        f32x4 acc1 = {0.f, 0.f, 0.f, 0.f};
        f32x4 acc2 = {0.f, 0.f, 0.f, 0.f};
        f32x4 acc3 = {0.f, 0.f, 0.f, 0.f};

        // depth-3 prefetch of the streamed tier, issued before any MFMA so
        // the pinned+LDS phases (~350 cyc) cover first-load L2 latency.
        uint4 sf[STR_KS][4];
        #pragma unroll
        for (int p = 0; p < 3; ++p)
            #pragma unroll
            for (int n = 0; n < 4; ++n)
                sf[p][n] = Pst[p * 4 * RH + n * 16];

        // ---- pinned k-steps 0..1
        #pragma unroll
        for (int c = 0; c < PIN_KS; ++c) {
            half8 a = bc8(thq[4 * c + g]);     // A = th broadcast to all rows
            acc0 = MFMA(a, bc8(bp[c][0]), acc0);
            acc1 = MFMA(a, bc8(bp[c][1]), acc1);
            acc2 = MFMA(a, bc8(bp[c][2]), acc2);
            acc3 = MFMA(a, bc8(bp[c][3]), acc3);
        }
        // ---- LDS k-steps 2..5
        #pragma unroll
        for (int c = 0; c < LDS_KS; ++c) {
            half8 a = bc8(thq[8 + 4 * c + g]);
            const uint4* wl = &Wl[(4 * c + g) * RH + wb + li];
            uint4 w0 = wl[0], w1 = wl[16], w2 = wl[32], w3 = wl[48];
            acc0 = MFMA(a, bc8(w0), acc0);
            acc1 = MFMA(a, bc8(w1), acc1);
            acc2 = MFMA(a, bc8(w2), acc2);
            acc3 = MFMA(a, bc8(w3), acc3);
        }
        // ---- streamed k-steps 6..17, rolling 3-ahead prefetch (full unroll
        // keeps every sf index compile-time-constant: no scratch)
        #pragma unroll
        for (int cc = 0; cc < STR_KS; ++cc) {
            if (cc + 3 < STR_KS) {
                #pragma unroll
                for (int n = 0; n < 4; ++n)
                    sf[cc + 3][n] = Pst[(cc + 3) * 4 * RH + n * 16];
            }
            half8 a = bc8(thq[24 + 4 * cc + g]);
            acc0 = MFMA(a, bc8(sf[cc][0]), acc0);
            acc1 = MFMA(a, bc8(sf[cc][1]), acc1);
            acc2 = MFMA(a, bc8(sf[cc][2]), acc2);
            acc3 = MFMA(a, bc8(sf[cc][3]), acc3);
        }

        // lane l holds every tile's fragment; its col lives in tile g.
        // Rows are identical (A-broadcast) -> element .x of the right tile.
        float a = (g < 2) ? ((g == 0) ? acc0.x : acc1.x)
                          : ((g == 2) ? acc2.x : acc3.x);

        float hn = C1F * h + C2F * a + sg;
        orow[(size_t)t * RH + col] = hn;
        h = hn;

        float e2 = __expf(2.0f * hn);
        thw[col] = (_Float16)(1.0f - 2.0f / (e2 + 1.0f));
        if (tid < RI && t + 1 < RT) thw[RH + tid] = (_Float16)xn;
        __syncthreads();
    }

    out[(size_t)RB * RT * RH + (size_t)b * RH + col] = h;
}

extern "C" void kernel_launch(void* const* d_in, const int* in_sizes, int n_in,
                              void* d_out, int out_size, void* d_ws, size_t ws_size,
                              hipStream_t stream) {
    const float* x   = (const float*)d_in[0];
    const float* Win = (const float*)d_in[1];
    const float* Wh  = (const float*)d_in[2];
    const float* sg  = (const float*)d_in[3];
    const float* h0  = (const float*)d_in[4];
    float* out = (float*)d_out;

    h2f* P = (h2f*)d_ws;   // 576 KB packed [W_hidden; W_in]

    const int n_entries = NU * RH * 4;
    hipLaunchKernelGGL(prep_pack, dim3((n_entries + 255) / 256), dim3(256), 0, stream,
                       Wh, Win, P);
    hipLaunchKernelGGL(rnn_scan, dim3(RB), dim3(RH), 0, stream,
                       x, sg, h0, (const uint4*)d_ws, out);
}

// Round 8
// 5189.582 us; speedup vs baseline: 7.2623x; 1.2881x over previous
//
#include <hip/hip_runtime.h>
#include <hip/hip_fp16.h>

typedef _Float16 h2f  __attribute__((ext_vector_type(2)));
typedef _Float16 half8 __attribute__((ext_vector_type(8)));
typedef float    f32x4 __attribute__((ext_vector_type(4)));

#define RB 64
#define RT 2048
#define RI 64
#define RH 512
#define C1F 0.9f
#define C2F 0.1f

// 72 u-groups of 8 k-rows (64 W_hidden + 8 W_in) = 18 MFMA k-steps of 32.
#define NU      72
#define PIN_KS  6     // k-steps 0..5   (u 0..23)  -> pinned VGPR B-frags (96 regs)
#define LDS_KS  4     // k-steps 6..9   (u 24..39) -> LDS-resident (128 KB)
#define STR_KS  8     // k-steps 10..17 (u 40..71) -> streamed (256 KB/step)
#define THL     (RH + RI)   // extended state [tanh(h); x_t] = 576 halves

static __device__ __forceinline__ half8 bc8(uint4 v) {
    return __builtin_bit_cast(half8, v);
}

#define MFMA(a, b, c) __builtin_amdgcn_mfma_f32_16x16x32_f16((a), (b), (c), 0, 0, 0)

// Pack [W_hidden; W_in] to f16, plain [u][j]: uint4 entry u*RH+j holds rows
// 8u..8u+7 of column j. Simultaneously a coalesced 16B-lane-stride stream
// layout and one MFMA B-subfragment per (k-step, col-tile):
// lane l -> P[(4c + (l>>4))*RH + cb + (l&15)].
__global__ void prep_pack(const float* __restrict__ W, const float* __restrict__ Win,
                          h2f* __restrict__ P) {
    int e = blockIdx.x * 256 + threadIdx.x;
    if (e >= NU * RH * 4) return;
    int q = e & 3;
    int j = (e >> 2) & (RH - 1);
    int u = e >> 11;
    int k = 8 * u + 2 * q;
    float v0, v1;
    if (u < 64) { v0 = W[k * RH + j];          v1 = W[(k + 1) * RH + j]; }
    else        { int i = k - RH;
                  v0 = Win[i * RH + j];        v1 = Win[(i + 1) * RH + j]; }
    h2f r; r.x = (_Float16)v0; r.y = (_Float16)v1;
    P[e] = r;
}

// One block per batch element; 8 waves; wave w owns cols w*64..w*64+63;
// lane l finalizes col w*64+l (C/D col=lane&15; rows identical by A-broadcast;
// layout verified end-to-end in round 7, absmax 0.0078).
// W column tiers: 96 pinned VGPRs + 128 KB LDS + 256 KB/step L2 stream.
__global__
__attribute__((amdgpu_flat_work_group_size(512, 512), amdgpu_waves_per_eu(2, 2)))
void rnn_scan(
        const float* __restrict__ x,      // [RB][RT][RI] f32
        const float* __restrict__ sigma,  // [RB][RT][RH] f32
        const float* __restrict__ h0,     // [RB][RH]     f32
        const uint4* __restrict__ P,      // packed f16 W (see prep_pack)
        float* __restrict__ out)          // [RB][RT][RH] f32, then h_f [RB][RH]
{
    const int b    = blockIdx.x;
    const int tid  = threadIdx.x;
    const int wave = tid >> 6;
    const int lane = tid & 63;
    const int g    = lane >> 4;          // B k-subrow group
    const int li   = lane & 15;          // B/C column within tile
    const int wb   = wave * 64;          // wave's column base
    const int col  = wb + lane;          // this lane's output column

    __shared__ __align__(16) uint4    Wl[LDS_KS * 4 * RH];  // 131072 B
    __shared__ __align__(16) _Float16 th[2][THL];           // 2304 B

    // LDS tier: u-groups 24..39 (k-steps 6..9)
    for (int e = tid; e < LDS_KS * 4 * RH; e += RH)
        Wl[e] = P[24 * RH + e];

    // pinned B-frags: k-steps 0..5, tiles n=0..3 (asm pin: non-rematerializable)
    uint4 bp[PIN_KS][4];
    #pragma unroll
    for (int c = 0; c < PIN_KS; ++c)
        #pragma unroll
        for (int n = 0; n < 4; ++n)
            bp[c][n] = P[(4 * c + g) * RH + wb + n * 16 + li];
    #pragma unroll
    for (int c = 0; c < PIN_KS; ++c)
        #pragma unroll
        for (int n = 0; n < 4; ++n)
            asm volatile("" : "+v"(bp[c][n].x), "+v"(bp[c][n].y),
                               "+v"(bp[c][n].z), "+v"(bp[c][n].w));

    const float* xrow = x + (size_t)b * RT * RI;
    const float* srow = sigma + (size_t)b * RT * RH;
    float*       orow = out + (size_t)b * RT * RH;

    float h = h0[b * RH + col];
    {
        float e2 = __expf(2.0f * h);
        th[0][col] = (_Float16)(1.0f - 2.0f / (e2 + 1.0f));
    }
    if (tid < RI) th[0][RH + tid] = (_Float16)xrow[tid];
    __syncthreads();

    for (int t = 0; t < RT; ++t) {
        const uint4* thq = (const uint4*)th[t & 1];
        _Float16*    thw = th[(t & 1) ^ 1];

        float sg = srow[(size_t)t * RH + col];
        float xn = 0.0f;
        if (tid < RI && t + 1 < RT) xn = xrow[(size_t)(t + 1) * RI + tid];

        // streamed tier base; opaque 0 keeps the 32 loads inside the t-loop
        int off0 = 0;
        asm volatile("" : "+v"(off0));
        const uint4* Pst = P + (size_t)(40 + g) * RH + wb + li + off0;

        f32x4 acc0 = {0.f, 0.f, 0.f, 0.f};
        f32x4 acc1 = {0.f, 0.f, 0.f, 0.f};
        f32x4 acc2 = {0.f, 0.f, 0.f, 0.f};
        f32x4 acc3 = {0.f, 0.f, 0.f, 0.f};

        // depth-3 prefetch of the streamed tier, issued before any MFMA so
        // the pinned+LDS phases cover first-load L2 latency.
        uint4 sf[STR_KS][4];
        #pragma unroll
        for (int p = 0; p < 3; ++p)
            #pragma unroll
            for (int n = 0; n < 4; ++n)
                sf[p][n] = Pst[p * 4 * RH + n * 16];

        // ---- pinned k-steps 0..5
        #pragma unroll
        for (int c = 0; c < PIN_KS; ++c) {
            half8 a = bc8(thq[4 * c + g]);     // A = th broadcast to all rows
            acc0 = MFMA(a, bc8(bp[c][0]), acc0);
            acc1 = MFMA(a, bc8(bp[c][1]), acc1);
            acc2 = MFMA(a, bc8(bp[c][2]), acc2);
            acc3 = MFMA(a, bc8(bp[c][3]), acc3);
        }
        // ---- LDS k-steps 6..9
        #pragma unroll
        for (int c = 0; c < LDS_KS; ++c) {
            half8 a = bc8(thq[24 + 4 * c + g]);
            const uint4* wl = &Wl[(4 * c + g) * RH + wb + li];
            uint4 w0 = wl[0], w1 = wl[16], w2 = wl[32], w3 = wl[48];
            acc0 = MFMA(a, bc8(w0), acc0);
            acc1 = MFMA(a, bc8(w1), acc1);
            acc2 = MFMA(a, bc8(w2), acc2);
            acc3 = MFMA(a, bc8(w3), acc3);
        }
        // ---- streamed k-steps 10..17, rolling 3-ahead prefetch (full unroll:
        // every sf index compile-time-constant, no scratch)
        #pragma unroll
        for (int cc = 0; cc < STR_KS; ++cc) {
            if (cc + 3 < STR_KS) {
                #pragma unroll
                for (int n = 0; n < 4; ++n)
                    sf[cc + 3][n] = Pst[(cc + 3) * 4 * RH + n * 16];
            }
            half8 a = bc8(thq[40 + 4 * cc + g]);
            acc0 = MFMA(a, bc8(sf[cc][0]), acc0);
            acc1 = MFMA(a, bc8(sf[cc][1]), acc1);
            acc2 = MFMA(a, bc8(sf[cc][2]), acc2);
            acc3 = MFMA(a, bc8(sf[cc][3]), acc3);
        }

        // lane l's column lives in tile g; rows identical -> element .x
        float a = (g < 2) ? ((g == 0) ? acc0.x : acc1.x)
                          : ((g == 2) ? acc2.x : acc3.x);

        float hn = C1F * h + C2F * a + sg;
        orow[(size_t)t * RH + col] = hn;
        h = hn;

        float e2 = __expf(2.0f * hn);
        thw[col] = (_Float16)(1.0f - 2.0f / (e2 + 1.0f));
        if (tid < RI && t + 1 < RT) thw[RH + tid] = (_Float16)xn;
        __syncthreads();
    }

    out[(size_t)RB * RT * RH + (size_t)b * RH + col] = h;
}

extern "C" void kernel_launch(void* const* d_in, const int* in_sizes, int n_in,
                              void* d_out, int out_size, void* d_ws, size_t ws_size,
                              hipStream_t stream) {
    const float* x   = (const float*)d_in[0];
    const float* Win = (const float*)d_in[1];
    const float* Wh  = (const float*)d_in[2];
    const float* sg  = (const float*)d_in[3];
    const float* h0  = (const float*)d_in[4];
    float* out = (float*)d_out;

    h2f* P = (h2f*)d_ws;   // 576 KB packed [W_hidden; W_in]

    const int n_entries = NU * RH * 4;
    hipLaunchKernelGGL(prep_pack, dim3((n_entries + 255) / 256), dim3(256), 0, stream,
                       Wh, Win, P);
    hipLaunchKernelGGL(rnn_scan, dim3(RB), dim3(512), 0, stream,
                       x, sg, h0, (const uint4*)d_ws, out);
}

// Round 9
// 3847.420 us; speedup vs baseline: 9.7958x; 1.3488x over previous
//
#include <hip/hip_runtime.h>
#include <hip/hip_fp16.h>

typedef _Float16 h2f   __attribute__((ext_vector_type(2)));
typedef _Float16 half8 __attribute__((ext_vector_type(8)));
typedef float    f32x4 __attribute__((ext_vector_type(4)));

#define RB 64
#define RT 2048
#define RI 64
#define RH 512
#define C1F 0.9f
#define C2F 0.1f

// W_hidden only (input projection precomputed into WIS): 64 u-groups of
// 8 k-rows = 16 MFMA k-steps of 32.
#define NU      64
#define PIN_KS  9    // k-steps 0..8   (u 0..35)  -> pinned in unified RF (144 regs, AGPR-backed)
#define LDS_KS  4    // k-steps 9..12  (u 36..51) -> LDS-resident (128 KB)
#define STR_KS  3    // k-steps 13..15 (u 52..63) -> streamed (96 KB/step)

static __device__ __forceinline__ half8 bc8(uint4 v) {
    return __builtin_bit_cast(half8, v);
}

#define MFMA(a, b, c) __builtin_amdgcn_mfma_f32_16x16x32_f16((a), (b), (c), 0, 0, 0)

// Pack W_hidden to f16, plain [u][j]: uint4 entry u*RH+j holds rows 8u..8u+7
// of column j. Coalesced 16B-lane-stride stream layout == MFMA B-subfragment:
// lane l of k-step c, col-tile cb -> P[(4c + (l>>4))*RH + cb + (l&15)].
__global__ void prep_pack(const float* __restrict__ W, h2f* __restrict__ P) {
    int e = blockIdx.x * 256 + threadIdx.x;
    if (e >= NU * RH * 4) return;
    int q = e & 3;
    int j = (e >> 2) & (RH - 1);
    int u = e >> 11;
    int k = 8 * u + 2 * q;
    h2f r;
    r.x = (_Float16)W[k * RH + j];
    r.y = (_Float16)W[(k + 1) * RH + j];
    P[e] = r;
}

// WIS[b,t,j] = C2 * sum_i x[b,t,i]*Win[i,j] + sigma[b,t,j], written into the
// [B][T][H] region of d_out (the scan reads each slot before overwriting it).
// 16 (b,t) rows per block amortize the Win-column register load.
#define WROWS 16
__global__ __launch_bounds__(512) void wis_gemm(
        const float* __restrict__ x, const float* __restrict__ Win,
        const float* __restrict__ sigma, float* __restrict__ outWIS) {
    const int j = threadIdx.x;
    const long r0 = (long)blockIdx.x * WROWS;
    __shared__ __align__(16) float xs[WROWS][RI];   // 4 KB

    for (int e = j; e < WROWS * RI; e += RH)
        (&xs[0][0])[e] = x[r0 * RI + e];

    float win[RI];                                   // Win column j in regs
    #pragma unroll
    for (int i = 0; i < RI; ++i) win[i] = Win[i * RH + j];
    #pragma unroll
    for (int i = 0; i < RI; ++i) asm volatile("" : "+v"(win[i]));  // no re-load

    __syncthreads();

    #pragma unroll 4
    for (int r = 0; r < WROWS; ++r) {
        float a = 0.f;
        #pragma unroll
        for (int i = 0; i < RI; ++i) a = fmaf(xs[r][i], win[i], a);
        long idx = (r0 + r) * RH + j;
        outWIS[idx] = fmaf(C2F, a, sigma[idx]);
    }
}

// One block per batch element; 8 waves; wave w owns cols w*64..w*64+63;
// lane l finalizes col w*64+l (A-broadcast MFMA, layout verified rounds 7/8).
// W tiers: 144 unified-RF regs + 128 KB LDS + 96 KB/step L2 stream.
__global__
__attribute__((amdgpu_flat_work_group_size(512, 512), amdgpu_waves_per_eu(2, 2)))
void rnn_scan(
        const float* __restrict__ h0,     // [RB][RH] f32
        const uint4* __restrict__ P,      // packed f16 W_hidden
        float* __restrict__ out)          // [RB][RT][RH] holds WIS on entry;
                                          // overwritten with h; then h_f tail
{
    const int b    = blockIdx.x;
    const int tid  = threadIdx.x;
    const int wave = tid >> 6;
    const int lane = tid & 63;
    const int g    = lane >> 4;          // B k-subrow group
    const int li   = lane & 15;          // B/C column within tile
    const int wb   = wave * 64;
    const int col  = wb + lane;

    __shared__ __align__(16) uint4    Wl[LDS_KS * 4 * RH];  // 131072 B
    __shared__ __align__(16) _Float16 th[2][RH];            // 2048 B

    // LDS tier: u-groups 36..51 (k-steps 9..12)
    for (int e = tid; e < LDS_KS * 4 * RH; e += RH)
        Wl[e] = P[PIN_KS * 4 * RH + e];

    // pinned B-frags: k-steps 0..8 (asm pin -> non-rematerializable; the
    // allocator backs these with AGPRs, which MFMA reads directly)
    uint4 bp[PIN_KS][4];
    #pragma unroll
    for (int c = 0; c < PIN_KS; ++c)
        #pragma unroll
        for (int n = 0; n < 4; ++n)
            bp[c][n] = P[(4 * c + g) * RH + wb + n * 16 + li];
    #pragma unroll
    for (int c = 0; c < PIN_KS; ++c)
        #pragma unroll
        for (int n = 0; n < 4; ++n)
            asm volatile("" : "+v"(bp[c][n].x), "+v"(bp[c][n].y),
                               "+v"(bp[c][n].z), "+v"(bp[c][n].w));

    float* orow = out + (size_t)b * RT * RH;

    float h = h0[b * RH + col];
    {
        float e2 = __expf(2.0f * h);
        th[0][col] = (_Float16)(1.0f - 2.0f / (e2 + 1.0f));
    }
    __syncthreads();

    for (int t = 0; t < RT; ++t) {
        const uint4* thq = (const uint4*)th[t & 1];
        _Float16*    thw = th[(t & 1) ^ 1];

        // own slot: WIS = c2*(x@Win)+sigma, precomputed; read before write.
        float wis = orow[(size_t)t * RH + col];

        // streamed tier base; opaque 0 keeps the 12 loads inside the t-loop
        int off0 = 0;
        asm volatile("" : "+v"(off0));
        const uint4* Pst =
            P + (size_t)((PIN_KS + LDS_KS) * 4 + g) * RH + wb + li + off0;

        // issue all streamed loads up front; consumed last -> L2 latency
        // covered by the pinned+LDS MFMA phases.
        uint4 sf[STR_KS][4];
        #pragma unroll
        for (int cc = 0; cc < STR_KS; ++cc)
            #pragma unroll
            for (int n = 0; n < 4; ++n)
                sf[cc][n] = Pst[cc * 4 * RH + n * 16];

        f32x4 acc0 = {0.f, 0.f, 0.f, 0.f};
        f32x4 acc1 = {0.f, 0.f, 0.f, 0.f};
        f32x4 acc2 = {0.f, 0.f, 0.f, 0.f};
        f32x4 acc3 = {0.f, 0.f, 0.f, 0.f};

        // ---- pinned k-steps 0..8
        #pragma unroll
        for (int c = 0; c < PIN_KS; ++c) {
            half8 a = bc8(thq[4 * c + g]);     // A = th broadcast to all rows
            acc0 = MFMA(a, bc8(bp[c][0]), acc0);
            acc1 = MFMA(a, bc8(bp[c][1]), acc1);
            acc2 = MFMA(a, bc8(bp[c][2]), acc2);
            acc3 = MFMA(a, bc8(bp[c][3]), acc3);
        }
        // ---- LDS k-steps 9..12
        #pragma unroll
        for (int c = 0; c < LDS_KS; ++c) {
            half8 a = bc8(thq[4 * (PIN_KS + c) + g]);
            const uint4* wl = &Wl[(4 * c + g) * RH + wb + li];
            uint4 w0 = wl[0], w1 = wl[16], w2 = wl[32], w3 = wl[48];
            acc0 = MFMA(a, bc8(w0), acc0);
            acc1 = MFMA(a, bc8(w1), acc1);
            acc2 = MFMA(a, bc8(w2), acc2);
            acc3 = MFMA(a, bc8(w3), acc3);
        }
        // ---- streamed k-steps 13..15
        #pragma unroll
        for (int cc = 0; cc < STR_KS; ++cc) {
            half8 a = bc8(thq[4 * (PIN_KS + LDS_KS + cc) + g]);
            acc0 = MFMA(a, bc8(sf[cc][0]), acc0);
            acc1 = MFMA(a, bc8(sf[cc][1]), acc1);
            acc2 = MFMA(a, bc8(sf[cc][2]), acc2);
            acc3 = MFMA(a, bc8(sf[cc][3]), acc3);
        }

        // lane l's column lives in tile g; rows identical -> element .x
        float a = (g < 2) ? ((g == 0) ? acc0.x : acc1.x)
                          : ((g == 2) ? acc2.x : acc3.x);

        float hn = fmaf(C1F, h, fmaf(C2F, a, wis));
        orow[(size_t)t * RH + col] = hn;
        h = hn;

        float e2 = __expf(2.0f * hn);
        thw[col] = (_Float16)(1.0f - 2.0f / (e2 + 1.0f));
        __syncthreads();
    }

    out[(size_t)RB * RT * RH + (size_t)b * RH + col] = h;
}

extern "C" void kernel_launch(void* const* d_in, const int* in_sizes, int n_in,
                              void* d_out, int out_size, void* d_ws, size_t ws_size,
                              hipStream_t stream) {
    const float* x   = (const float*)d_in[0];
    const float* Win = (const float*)d_in[1];
    const float* Wh  = (const float*)d_in[2];
    const float* sg  = (const float*)d_in[3];
    const float* h0  = (const float*)d_in[4];
    float* out = (float*)d_out;

    h2f* P = (h2f*)d_ws;   // 512 KB packed W_hidden

    const int n_entries = NU * RH * 4;
    hipLaunchKernelGGL(prep_pack, dim3((n_entries + 255) / 256), dim3(256), 0, stream,
                       Wh, P);
    hipLaunchKernelGGL(wis_gemm, dim3(RB * RT / WROWS), dim3(RH), 0, stream,
                       x, Win, sg, out);
    hipLaunchKernelGGL(rnn_scan, dim3(RB), dim3(RH), 0, stream,
                       h0, (const uint4*)d_ws, out);
}

// Round 10
// 3547.849 us; speedup vs baseline: 10.6229x; 1.0844x over previous
//
#include <hip/hip_runtime.h>
#include <hip/hip_fp16.h>

typedef _Float16 h2f   __attribute__((ext_vector_type(2)));
typedef _Float16 half8 __attribute__((ext_vector_type(8)));
typedef float    f32x4 __attribute__((ext_vector_type(4)));

#define RB 64
#define RT 2048
#define RI 64
#define RH 512
#define C1F 0.9f
#define C2F 0.1f

// W_hidden only (input projection precomputed into WIS): 64 u-groups of
// 8 k-rows = 16 MFMA k-steps of 32. Fully on-chip: no per-step W streaming.
#define NU      64
#define PIN_KS  12   // k-steps 0..11  (u 0..47)  -> pinned unified-RF B-frags (192 regs, AGPR-backed)
#define LDS_KS  4    // k-steps 12..15 (u 48..63) -> LDS-resident (128 KB)

static __device__ __forceinline__ half8 bc8(uint4 v) {
    return __builtin_bit_cast(half8, v);
}

#define MFMA(a, b, c) __builtin_amdgcn_mfma_f32_16x16x32_f16((a), (b), (c), 0, 0, 0)

// Pack W_hidden to f16, plain [u][j]: uint4 entry u*RH+j holds rows 8u..8u+7
// of column j == MFMA B-subfragment: lane l of k-step c, col-tile cb ->
// P[(4c + (l>>4))*RH + cb + (l&15)].
__global__ void prep_pack(const float* __restrict__ W, h2f* __restrict__ P) {
    int e = blockIdx.x * 256 + threadIdx.x;
    if (e >= NU * RH * 4) return;
    int q = e & 3;
    int j = (e >> 2) & (RH - 1);
    int u = e >> 11;
    int k = 8 * u + 2 * q;
    h2f r;
    r.x = (_Float16)W[k * RH + j];
    r.y = (_Float16)W[(k + 1) * RH + j];
    P[e] = r;
}

// WIS[b,t,j] = C2 * sum_i x[b,t,i]*Win[i,j] + sigma[b,t,j], written into the
// [B][T][H] region of d_out (the scan reads each slot before overwriting it).
// 4 independent fma chains break the 64-deep dependency (round-9 pre-pass was
// latency-bound at ~2x issue floor).
#define WROWS 16
__global__ __launch_bounds__(512) void wis_gemm(
        const float* __restrict__ x, const float* __restrict__ Win,
        const float* __restrict__ sigma, float* __restrict__ outWIS) {
    const int j = threadIdx.x;
    const long r0 = (long)blockIdx.x * WROWS;
    __shared__ __align__(16) float xs[WROWS][RI];   // 4 KB

    for (int e = j; e < WROWS * RI; e += RH)
        (&xs[0][0])[e] = x[r0 * RI + e];

    float win[RI];                                   // Win column j in regs
    #pragma unroll
    for (int i = 0; i < RI; ++i) win[i] = Win[i * RH + j];
    #pragma unroll
    for (int i = 0; i < RI; ++i) asm volatile("" : "+v"(win[i]));  // no re-load

    __syncthreads();

    #pragma unroll 4
    for (int r = 0; r < WROWS; ++r) {
        float a0 = 0.f, a1 = 0.f, a2 = 0.f, a3 = 0.f;
        #pragma unroll
        for (int i = 0; i < RI / 4; ++i) {
            a0 = fmaf(xs[r][4 * i + 0], win[4 * i + 0], a0);
            a1 = fmaf(xs[r][4 * i + 1], win[4 * i + 1], a1);
            a2 = fmaf(xs[r][4 * i + 2], win[4 * i + 2], a2);
            a3 = fmaf(xs[r][4 * i + 3], win[4 * i + 3], a3);
        }
        long idx = (r0 + r) * RH + j;
        outWIS[idx] = fmaf(C2F, (a0 + a1) + (a2 + a3), sigma[idx]);
    }
}

// One block per batch element; 8 waves; wave w owns cols w*64..w*64+63;
// lane l finalizes col w*64+l (A-broadcast MFMA, layout verified rounds 7-9).
// W fully on-chip: 192 unified-RF regs + 128 KB LDS. Per-step global traffic
// is just the WIS read and the h write.
__global__
__attribute__((amdgpu_flat_work_group_size(512, 512), amdgpu_waves_per_eu(2, 2)))
void rnn_scan(
        const float* __restrict__ h0,     // [RB][RH] f32
        const uint4* __restrict__ P,      // packed f16 W_hidden
        float* __restrict__ out)          // [RB][RT][RH] holds WIS on entry;
                                          // overwritten with h; then h_f tail
{
    const int b    = blockIdx.x;
    const int tid  = threadIdx.x;
    const int wave = tid >> 6;
    const int lane = tid & 63;
    const int g    = lane >> 4;          // B k-subrow group
    const int li   = lane & 15;          // B/C column within tile
    const int wb   = wave * 64;
    const int col  = wb + lane;

    __shared__ __align__(16) uint4    Wl[LDS_KS * 4 * RH];  // 131072 B
    __shared__ __align__(16) _Float16 th[2][RH];            // 2048 B

    // LDS tier: u-groups 48..63 (k-steps 12..15)
    for (int e = tid; e < LDS_KS * 4 * RH; e += RH)
        Wl[e] = P[PIN_KS * 4 * RH + e];

    // pinned B-frags: k-steps 0..11 (asm pin -> non-rematerializable; the
    // allocator backs these with AGPRs, which MFMA reads directly)
    uint4 bp[PIN_KS][4];
    #pragma unroll
    for (int c = 0; c < PIN_KS; ++c)
        #pragma unroll
        for (int n = 0; n < 4; ++n)
            bp[c][n] = P[(4 * c + g) * RH + wb + n * 16 + li];
    #pragma unroll
    for (int c = 0; c < PIN_KS; ++c)
        #pragma unroll
        for (int n = 0; n < 4; ++n)
            asm volatile("" : "+v"(bp[c][n].x), "+v"(bp[c][n].y),
                               "+v"(bp[c][n].z), "+v"(bp[c][n].w));

    float* orow = out + (size_t)b * RT * RH;

    float h = h0[b * RH + col];
    {
        float e2 = __expf(2.0f * h);
        th[0][col] = (_Float16)(1.0f - 2.0f / (e2 + 1.0f));
    }
    __syncthreads();

    for (int t = 0; t < RT; ++t) {
        const uint4* thq = (const uint4*)th[t & 1];
        _Float16*    thw = th[(t & 1) ^ 1];

        // own slot: WIS = c2*(x@Win)+sigma, precomputed; read before write.
        // Issued first, consumed last -> HBM latency hidden under MFMA.
        float wis = orow[(size_t)t * RH + col];

        f32x4 acc0 = {0.f, 0.f, 0.f, 0.f};
        f32x4 acc1 = {0.f, 0.f, 0.f, 0.f};
        f32x4 acc2 = {0.f, 0.f, 0.f, 0.f};
        f32x4 acc3 = {0.f, 0.f, 0.f, 0.f};

        // ---- pinned k-steps 0..11 (B operands read straight from AGPRs)
        #pragma unroll
        for (int c = 0; c < PIN_KS; ++c) {
            half8 a = bc8(thq[4 * c + g]);     // A = th broadcast to all rows
            acc0 = MFMA(a, bc8(bp[c][0]), acc0);
            acc1 = MFMA(a, bc8(bp[c][1]), acc1);
            acc2 = MFMA(a, bc8(bp[c][2]), acc2);
            acc3 = MFMA(a, bc8(bp[c][3]), acc3);
        }
        // ---- LDS k-steps 12..15
        #pragma unroll
        for (int c = 0; c < LDS_KS; ++c) {
            half8 a = bc8(thq[4 * (PIN_KS + c) + g]);
            const uint4* wl = &Wl[(4 * c + g) * RH + wb + li];
            uint4 w0 = wl[0], w1 = wl[16], w2 = wl[32], w3 = wl[48];
            acc0 = MFMA(a, bc8(w0), acc0);
            acc1 = MFMA(a, bc8(w1), acc1);
            acc2 = MFMA(a, bc8(w2), acc2);
            acc3 = MFMA(a, bc8(w3), acc3);
        }

        // lane l's column lives in tile g; rows identical -> element .x
        float a = (g < 2) ? ((g == 0) ? acc0.x : acc1.x)
                          : ((g == 2) ? acc2.x : acc3.x);

        float hn = fmaf(C1F, h, fmaf(C2F, a, wis));
        orow[(size_t)t * RH + col] = hn;
        h = hn;

        float e2 = __expf(2.0f * hn);
        thw[col] = (_Float16)(1.0f - 2.0f / (e2 + 1.0f));
        __syncthreads();
    }

    out[(size_t)RB * RT * RH + (size_t)b * RH + col] = h;
}

extern "C" void kernel_launch(void* const* d_in, const int* in_sizes, int n_in,
                              void* d_out, int out_size, void* d_ws, size_t ws_size,
                              hipStream_t stream) {
    const float* x   = (const float*)d_in[0];
    const float* Win = (const float*)d_in[1];
    const float* Wh  = (const float*)d_in[2];
    const float* sg  = (const float*)d_in[3];
    const float* h0  = (const float*)d_in[4];
    float* out = (float*)d_out;

    h2f* P = (h2f*)d_ws;   // 512 KB packed W_hidden

    const int n_entries = NU * RH * 4;
    hipLaunchKernelGGL(prep_pack, dim3((n_entries + 255) / 256), dim3(256), 0, stream,
                       Wh, P);
    hipLaunchKernelGGL(wis_gemm, dim3(RB * RT / WROWS), dim3(RH), 0, stream,
                       x, Win, sg, out);
    hipLaunchKernelGGL(rnn_scan, dim3(RB), dim3(RH), 0, stream,
                       h0, (const uint4*)d_ws, out);
}

// Round 11
// 3162.566 us; speedup vs baseline: 11.9170x; 1.1218x over previous
//
#include <hip/hip_runtime.h>
#include <hip/hip_fp16.h>

typedef _Float16 h2f   __attribute__((ext_vector_type(2)));
typedef _Float16 half8 __attribute__((ext_vector_type(8)));
typedef float    f32x4 __attribute__((ext_vector_type(4)));

#define RB 64
#define RT 2048
#define RI 64
#define RH 512
#define C1F 0.9f
#define C2F 0.1f

// W_hidden only (input projection precomputed into WIS): 64 u-groups of
// 8 k-rows = 16 MFMA k-steps of 32.
#define NU      64
#define PIN_KS  12   // k-steps 0..11  -> pinned unified-RF B-frags (192 regs, AGPR-backed)
#define LDS_KS  3    // k-steps 12..14 -> LDS-resident (96 KB)
#define STR_KS  1    // k-step  15     -> streamed, 32 KB/step, L1-resident
                     //                   (step-invariant addresses, idle vMEM port)

static __device__ __forceinline__ half8 bc8(uint4 v) {
    return __builtin_bit_cast(half8, v);
}

#define MFMA(a, b, c) __builtin_amdgcn_mfma_f32_16x16x32_f16((a), (b), (c), 0, 0, 0)

// Pack W_hidden to f16, plain [u][j]: uint4 entry u*RH+j holds rows 8u..8u+7
// of column j == MFMA B-subfragment: lane l of k-step c, col-tile cb ->
// P[(4c + (l>>4))*RH + cb + (l&15)].
__global__ void prep_pack(const float* __restrict__ W, h2f* __restrict__ P) {
    int e = blockIdx.x * 256 + threadIdx.x;
    if (e >= NU * RH * 4) return;
    int q = e & 3;
    int j = (e >> 2) & (RH - 1);
    int u = e >> 11;
    int k = 8 * u + 2 * q;
    h2f r;
    r.x = (_Float16)W[k * RH + j];
    r.y = (_Float16)W[(k + 1) * RH + j];
    P[e] = r;
}

// WIS[b,t,j] = C2 * sum_i x[b,t,i]*Win[i,j] + sigma[b,t,j], into d_out's
// [B][T][H] region (scan reads each slot before overwriting it).
// x rows are read with wave-uniform addresses -> scalar/constant-cache path
// (round-10 version staged x through LDS: 256 ds_reads/thread made the
// pre-pass LDS-port-bound at ~330us vs the ~86us HBM floor).
#define WROWS 8
__global__ __launch_bounds__(512) void wis_gemm(
        const float* __restrict__ x, const float* __restrict__ Win,
        const float* __restrict__ sigma, float* __restrict__ outWIS) {
    const int j = threadIdx.x;
    const long r0 = (long)blockIdx.x * WROWS;

    float win[RI];                                   // Win column j in regs
    #pragma unroll
    for (int i = 0; i < RI; ++i) win[i] = Win[i * RH + j];
    #pragma unroll
    for (int i = 0; i < RI; ++i) asm volatile("" : "+v"(win[i]));  // no re-load

    #pragma unroll
    for (int r = 0; r < WROWS; ++r) {
        const float* xr = x + (r0 + r) * RI;         // wave-uniform row base
        float a0 = 0.f, a1 = 0.f, a2 = 0.f, a3 = 0.f;
        #pragma unroll
        for (int i = 0; i < RI / 4; ++i) {
            a0 = fmaf(xr[4 * i + 0], win[4 * i + 0], a0);
            a1 = fmaf(xr[4 * i + 1], win[4 * i + 1], a1);
            a2 = fmaf(xr[4 * i + 2], win[4 * i + 2], a2);
            a3 = fmaf(xr[4 * i + 3], win[4 * i + 3], a3);
        }
        long idx = (r0 + r) * RH + j;
        outWIS[idx] = fmaf(C2F, (a0 + a1) + (a2 + a3), sigma[idx]);
    }
}

// One block per batch element; 8 waves; wave w owns cols w*64..w*64+63;
// lane l finalizes col w*64+l (A-broadcast MFMA, layout verified rounds 7-10).
// W tiers: 192 unified-RF regs + 96 KB LDS + 32 KB/step L1-resident stream.
__global__
__attribute__((amdgpu_flat_work_group_size(512, 512), amdgpu_waves_per_eu(2, 2)))
void rnn_scan(
        const float* __restrict__ h0,     // [RB][RH] f32
        const uint4* __restrict__ P,      // packed f16 W_hidden
        float* __restrict__ out)          // [RB][RT][RH] holds WIS on entry;
                                          // overwritten with h; then h_f tail
{
    const int b    = blockIdx.x;
    const int tid  = threadIdx.x;
    const int wave = tid >> 6;
    const int lane = tid & 63;
    const int g    = lane >> 4;          // B k-subrow group
    const int li   = lane & 15;          // B/C column within tile
    const int wb   = wave * 64;
    const int col  = wb + lane;

    __shared__ __align__(16) uint4    Wl[LDS_KS * 4 * RH];  // 98304 B
    __shared__ __align__(16) _Float16 th[2][RH];            // 2048 B

    // LDS tier: k-steps 12..14
    for (int e = tid; e < LDS_KS * 4 * RH; e += RH)
        Wl[e] = P[PIN_KS * 4 * RH + e];

    // pinned B-frags: k-steps 0..11 (asm pin -> non-rematerializable; backed
    // by the AGPR half of the unified RF, read directly by MFMA)
    uint4 bp[PIN_KS][4];
    #pragma unroll
    for (int c = 0; c < PIN_KS; ++c)
        #pragma unroll
        for (int n = 0; n < 4; ++n)
            bp[c][n] = P[(4 * c + g) * RH + wb + n * 16 + li];
    #pragma unroll
    for (int c = 0; c < PIN_KS; ++c)
        #pragma unroll
        for (int n = 0; n < 4; ++n)
            asm volatile("" : "+v"(bp[c][n].x), "+v"(bp[c][n].y),
                               "+v"(bp[c][n].z), "+v"(bp[c][n].w));

    float* orow = out + (size_t)b * RT * RH;

    float h = h0[b * RH + col];
    {
        float e2 = __expf(2.0f * h);
        th[0][col] = (_Float16)(1.0f - 2.0f / (e2 + 1.0f));
    }
    __syncthreads();

    for (int t = 0; t < RT; ++t) {
        const uint4* thq = (const uint4*)th[t & 1];
        _Float16*    thw = th[(t & 1) ^ 1];

        // own slot: WIS = c2*(x@Win)+sigma, precomputed; read before write.
        float wis = orow[(size_t)t * RH + col];

        // streamed k-step 15: step-invariant 32 KB window -> L1 hits after
        // step 0; rides the otherwise-idle vector-memory port. Opaque 0
        // keeps the loads inside the t-loop (would otherwise hoist into 16
        // more pinned regs and risk the round-3 spill).
        int off0 = 0;
        asm volatile("" : "+v"(off0));
        const uint4* Pst =
            P + (size_t)((PIN_KS + LDS_KS) * 4 + g) * RH + wb + li + off0;
        uint4 sf0 = Pst[0], sf1 = Pst[16], sf2 = Pst[32], sf3 = Pst[48];

        f32x4 acc0 = {0.f, 0.f, 0.f, 0.f};
        f32x4 acc1 = {0.f, 0.f, 0.f, 0.f};
        f32x4 acc2 = {0.f, 0.f, 0.f, 0.f};
        f32x4 acc3 = {0.f, 0.f, 0.f, 0.f};

        // ---- pinned k-steps 0..11 (B operands read straight from AGPRs)
        #pragma unroll
        for (int c = 0; c < PIN_KS; ++c) {
            half8 a = bc8(thq[4 * c + g]);     // A = th broadcast to all rows
            acc0 = MFMA(a, bc8(bp[c][0]), acc0);
            acc1 = MFMA(a, bc8(bp[c][1]), acc1);
            acc2 = MFMA(a, bc8(bp[c][2]), acc2);
            acc3 = MFMA(a, bc8(bp[c][3]), acc3);
        }
        // ---- LDS k-steps 12..14
        #pragma unroll
        for (int c = 0; c < LDS_KS; ++c) {
            half8 a = bc8(thq[4 * (PIN_KS + c) + g]);
            const uint4* wl = &Wl[(4 * c + g) * RH + wb + li];
            uint4 w0 = wl[0], w1 = wl[16], w2 = wl[32], w3 = wl[48];
            acc0 = MFMA(a, bc8(w0), acc0);
            acc1 = MFMA(a, bc8(w1), acc1);
            acc2 = MFMA(a, bc8(w2), acc2);
            acc3 = MFMA(a, bc8(w3), acc3);
        }
        // ---- streamed k-step 15 (loads issued at loop top, consumed last)
        {
            half8 a = bc8(thq[4 * (PIN_KS + LDS_KS) + g]);
            acc0 = MFMA(a, bc8(sf0), acc0);
            acc1 = MFMA(a, bc8(sf1), acc1);
            acc2 = MFMA(a, bc8(sf2), acc2);
            acc3 = MFMA(a, bc8(sf3), acc3);
        }

        // lane l's column lives in tile g; rows identical -> element .x
        float a = (g < 2) ? ((g == 0) ? acc0.x : acc1.x)
                          : ((g == 2) ? acc2.x : acc3.x);

        float hn = fmaf(C1F, h, fmaf(C2F, a, wis));
        orow[(size_t)t * RH + col] = hn;
        h = hn;

        float e2 = __expf(2.0f * hn);
        thw[col] = (_Float16)(1.0f - 2.0f / (e2 + 1.0f));
        __syncthreads();
    }

    out[(size_t)RB * RT * RH + (size_t)b * RH + col] = h;
}

extern "C" void kernel_launch(void* const* d_in, const int* in_sizes, int n_in,
                              void* d_out, int out_size, void* d_ws, size_t ws_size,
                              hipStream_t stream) {
    const float* x   = (const float*)d_in[0];
    const float* Win = (const float*)d_in[1];
    const float* Wh  = (const float*)d_in[2];
    const float* sg  = (const float*)d_in[3];
    const float* h0  = (const float*)d_in[4];
    float* out = (float*)d_out;

    h2f* P = (h2f*)d_ws;   // 512 KB packed W_hidden

    const int n_entries = NU * RH * 4;
    hipLaunchKernelGGL(prep_pack, dim3((n_entries + 255) / 256), dim3(256), 0, stream,
                       Wh, P);
    hipLaunchKernelGGL(wis_gemm, dim3(RB * RT / WROWS), dim3(RH), 0, stream,
                       x, Win, sg, out);
    hipLaunchKernelGGL(rnn_scan, dim3(RB), dim3(RH), 0, stream,
                       h0, (const uint4*)d_ws, out);
}